// Round 10
// baseline (151.959 us; speedup 1.0000x reference)
//
#include <hip/hip_runtime.h>

#define NN 8000
#define NPAD 8064
#define NE 64000
#define INF 16
#define HH 128
#define MM 16
#define EDF 4
#define OUTF 4
#define NL 2
#define BN_EPS 1e-5f
#define BPR 2080          // Bp rows per layer: 2048 qn-cols + 16 b2-cols + 16 rootW-cols
#define CAP 48            // per-node edge bucket capacity (Poisson(8): P(deg>=48)~1e-20)

typedef __attribute__((ext_vector_type(8))) short short8;
typedef __attribute__((ext_vector_type(4))) float f32x4;

static __device__ __forceinline__ unsigned short f2bf(float f) {
  unsigned u = __builtin_bit_cast(unsigned, f);
  u = (u + 0x7fffu + ((u >> 16) & 1u)) >> 16;
  return (unsigned short)u;
}
static __device__ __forceinline__ float bf2f(unsigned short s) {
  unsigned u = ((unsigned)s) << 16;
  return __builtin_bit_cast(float, u);
}

// bijective k-permutation for contract LDS layout, and its inverse
static __device__ __forceinline__ int qperm(int k) {
  return ((k >> 3) & 3) | ((k & 7) << 2) | (k & 0x60);
}
static __device__ __forceinline__ int qinv(int r) {
  return ((r & 3) << 3) | ((r >> 2) & 7) | (r & 0x60);
}

// in_proj (all blocks) + edge bucket-scatter (0..499) + Bp build (500..759) + agg zero (760..884)
__global__ __launch_bounds__(128) void front_k(
    const float* __restrict__ x, const float* __restrict__ inW,
    const float* __restrict__ inb, const int* __restrict__ ei,
    const float* __restrict__ ea,
    const float* __restrict__ W2, const float* __restrict__ b2,
    const float* __restrict__ rW,
    unsigned short* __restrict__ hb,
    float* __restrict__ deg, int* __restrict__ cnt,
    unsigned short* __restrict__ Bp, float* __restrict__ agg,
    float* __restrict__ ea_s, int* __restrict__ dst_s) {
  int blk = blockIdx.x;
  int t = threadIdx.x;
  __shared__ float sx[INF];
  if (t < INF) sx[t] = x[blk * INF + t];
  __syncthreads();
  float acc = inb[t];
#pragma unroll
  for (int i = 0; i < INF; ++i) acc = fmaf(sx[i], inW[i * HH + t], acc);
  hb[(size_t)blk * HH + t] = f2bf(acc);

  if (blk < 500) {
    int e = blk * 128 + t;
    int src = ei[e], dst = ei[NE + e];
    atomicAdd(&deg[dst], 1.0f);
    int slot = atomicAdd(&cnt[src], 1);
    int p = src * CAP + slot;
    *(float4*)&ea_s[(size_t)p * 4] = *(const float4*)&ea[(size_t)e * 4];
    dst_s[p] = dst;
  } else if (blk < 756) {
    // transpose one W2 row k: read 2048 f32 contiguous, write 16 Bp rows coalesced
    int r = blk - 500;            // 0..255
    int l = r >> 7, k = r & 127;
    const float* w2row = W2 + (size_t)l * (HH * HH * MM) + (size_t)k * 2048;
    float4 v0 = *(const float4*)&w2row[t * 16 + 0];
    float4 v1 = *(const float4*)&w2row[t * 16 + 4];
    float4 v2 = *(const float4*)&w2row[t * 16 + 8];
    float4 v3 = *(const float4*)&w2row[t * 16 + 12];
    unsigned short* bpr = Bp + ((size_t)l * BPR + (size_t)k * 16) * HH + t;
#pragma unroll
    for (int j = 0; j < 4; ++j) bpr[(0 + j) * HH] = f2bf((&v0.x)[j]);
#pragma unroll
    for (int j = 0; j < 4; ++j) bpr[(4 + j) * HH] = f2bf((&v1.x)[j]);
#pragma unroll
    for (int j = 0; j < 4; ++j) bpr[(8 + j) * HH] = f2bf((&v2.x)[j]);
#pragma unroll
    for (int j = 0; j < 4; ++j) bpr[(12 + j) * HH] = f2bf((&v3.x)[j]);
  } else if (blk < 760) {
    // b2 rows (756,757) at Bp row 2048; rootW rows (758,759) at Bp row 2064
    int isroot = (blk >= 758);
    int l = (blk - 756) & 1;
    const float* src = isroot ? (rW + (size_t)l * HH * MM) : (b2 + (size_t)l * 2048);
    float4 v0 = *(const float4*)&src[t * 16 + 0];
    float4 v1 = *(const float4*)&src[t * 16 + 4];
    float4 v2 = *(const float4*)&src[t * 16 + 8];
    float4 v3 = *(const float4*)&src[t * 16 + 12];
    unsigned short* bpr = Bp + ((size_t)l * BPR + 2048 + isroot * 16) * HH + t;
#pragma unroll
    for (int j = 0; j < 4; ++j) bpr[(0 + j) * HH] = f2bf((&v0.x)[j]);
#pragma unroll
    for (int j = 0; j < 4; ++j) bpr[(4 + j) * HH] = f2bf((&v1.x)[j]);
#pragma unroll
    for (int j = 0; j < 4; ++j) bpr[(8 + j) * HH] = f2bf((&v2.x)[j]);
#pragma unroll
    for (int j = 0; j < 4; ++j) bpr[(12 + j) * HH] = f2bf((&v3.x)[j]);
  } else if (blk < 885) {
    // zero agg: 125 blocks x 128 thr x 2 uint4 = 32000 uint4 = NN*MM f32
    int i = (blk - 760) * 256 + t;
    uint4 z = make_uint4(0, 0, 0, 0);
    ((uint4*)agg)[i] = z;
    ((uint4*)agg)[i + 128] = z;
  }
}

// Qn[NPAD x 2048](bf16) = A[NPAD x 128] @ Bp^T ; grid (17, 63).
// bn<16: Qn cols (vectorized via LDS-transposed epilogue).
// bn==16: B2[NPAD x 16] and Xroot[NPAD x 16], f32.
__global__ __launch_bounds__(256) void gemm_qn_k(
    const unsigned short* __restrict__ hb, const float* __restrict__ hpre,
    const float* __restrict__ bnsums, const float* __restrict__ gamma,
    const float* __restrict__ beta, int bn_mode,
    const unsigned short* __restrict__ Bp,
    unsigned short* __restrict__ Qn, float* __restrict__ B2,
    float* __restrict__ Xroot) {
  __shared__ unsigned short sMem[32768];   // sA | sB ; reused as transpose buffer
  unsigned short* sA = sMem;
  unsigned short* sB = sMem + 16384;
  int tid = threadIdx.x;
  int bm = blockIdx.y, bn = blockIdx.x;
  int r0 = bm * 128;

  // ---- A staging ----
  if (bn_mode == 0) {
#pragma unroll
    for (int rr = 0; rr < 8; ++rr) {
      int s = rr * 256 + tid;
      int row = s >> 4, k8 = s & 15;
      int n = r0 + row;
      uint4 v = make_uint4(0, 0, 0, 0);
      if (n < NN) v = *(const uint4*)&hb[(size_t)n * HH + k8 * 8];
      *(uint4*)&sA[(s ^ ((s >> 4) & 7)) * 8] = v;
    }
  } else {
    int k8 = tid & 15;
    int c0 = k8 * 8;
    float scl[8], shf[8];
#pragma unroll
    for (int j = 0; j < 8; ++j) {
      int c = c0 + j;
      float mu = bnsums[c] * (1.0f / NN);
      float var = bnsums[HH + c] * (1.0f / NN) - mu * mu;
      float sc = gamma[c] * rsqrtf(var + BN_EPS);
      scl[j] = sc;
      shf[j] = beta[c] - mu * sc;
    }
#pragma unroll
    for (int rr = 0; rr < 8; ++rr) {
      int s = rr * 256 + tid;
      int row = s >> 4;
      int n = r0 + row;
      short8 o = {0, 0, 0, 0, 0, 0, 0, 0};
      if (n < NN) {
        float4 v0 = *(const float4*)&hpre[(size_t)n * HH + c0];
        float4 v1 = *(const float4*)&hpre[(size_t)n * HH + c0 + 4];
#pragma unroll
        for (int j = 0; j < 4; ++j) {
          o[j] = (short)f2bf(fmaxf(0.f, fmaf((&v0.x)[j], scl[j], shf[j])));
          o[4 + j] = (short)f2bf(fmaxf(0.f, fmaf((&v1.x)[j], scl[4 + j], shf[4 + j])));
        }
      }
      *(short8*)&sA[(s ^ ((s >> 4) & 7)) * 8] = o;
    }
  }

  // ---- B staging ----
  if (bn < 16) {
    const uint4* gB = (const uint4*)(Bp + (size_t)bn * 128 * HH);
#pragma unroll
    for (int rr = 0; rr < 8; ++rr) {
      int s = rr * 256 + tid;
      uint4 v = gB[s];
      *(uint4*)&sB[(s ^ ((s >> 4) & 7)) * 8] = v;
    }
  } else {
    const uint4* gB = (const uint4*)(Bp + (size_t)2048 * HH);
#pragma unroll
    for (int rr = 0; rr < 8; ++rr) {
      int s = rr * 256 + tid;
      int row = s >> 4;
      uint4 v = make_uint4(0, 0, 0, 0);
      if (row < 32) v = gB[s];
      *(uint4*)&sB[(s ^ ((s >> 4) & 7)) * 8] = v;
    }
  }
  __syncthreads();

  int wid = tid >> 6, lane = tid & 63;
  int wr = (wid >> 1) * 64;
  int wc = (wid & 1) * 64;
  int l15 = lane & 15, l4 = lane >> 4;

  f32x4 acc[4][4] = {};
#pragma unroll
  for (int ks = 0; ks < 4; ++ks) {
    short8 af[4], bfr[4];
    int kb = ks * 4 + l4;
#pragma unroll
    for (int mr = 0; mr < 4; ++mr) {
      int r = wr + mr * 16 + l15;
      af[mr] = *(const short8*)&sA[(r * 16 + (kb ^ (r & 7))) * 8];
    }
#pragma unroll
    for (int nc = 0; nc < 4; ++nc) {
      int r = wc + nc * 16 + l15;
      bfr[nc] = *(const short8*)&sB[(r * 16 + (kb ^ (r & 7))) * 8];
    }
#pragma unroll
    for (int mr = 0; mr < 4; ++mr)
#pragma unroll
      for (int nc = 0; nc < 4; ++nc)
        acc[mr][nc] = __builtin_amdgcn_mfma_f32_16x16x32_bf16(af[mr], bfr[nc], acc[mr][nc], 0, 0, 0);
  }

  if (bn < 16) {
    // LDS transpose epilogue: bf16 into [128][136] tile, then coalesced uint4 stores
    __syncthreads();
#pragma unroll
    for (int mr = 0; mr < 4; ++mr) {
      int r = wr + mr * 16 + l4 * 4;
#pragma unroll
      for (int nc = 0; nc < 4; ++nc) {
        int c = wc + nc * 16 + l15;
#pragma unroll
        for (int j = 0; j < 4; ++j)
          sMem[(r + j) * 136 + c] = f2bf(acc[mr][nc][j]);
      }
    }
    __syncthreads();
    int row = tid >> 1, c0h = (tid & 1) * 64;
    const uint4* srcp = (const uint4*)&sMem[row * 136 + c0h];
    uint4* dstp = (uint4*)&Qn[(size_t)(r0 + row) * (HH * MM) + bn * 128 + c0h];
#pragma unroll
    for (int j = 0; j < 8; ++j) dstp[j] = srcp[j];
  } else if (wc == 0) {
#pragma unroll
    for (int mr = 0; mr < 4; ++mr) {
      int rr0 = r0 + wr + mr * 16 + l4 * 4;
#pragma unroll
      for (int j = 0; j < 4; ++j) {
        B2[(size_t)(rr0 + j) * MM + l15] = acc[mr][0][j];
        Xroot[(size_t)(rr0 + j) * MM + l15] = acc[mr][1][j];
      }
    }
  }
}

// One wave per src node: P[d x 16] = relu1[d x 128] @ Qn[n][128 x 16] via MFMA.
// Bucketed edges; LDS staging linear ds_write + pre-permuted global source.
__global__ __launch_bounds__(256) void contract_k(const float* __restrict__ ea_s,
                                                  const int* __restrict__ dst_s,
                                                  const int* __restrict__ cnt,
                                                  const float* __restrict__ W1,
                                                  const float* __restrict__ b1,
                                                  const unsigned short* __restrict__ Qn,
                                                  const float* __restrict__ B2,
                                                  float* __restrict__ agg) {
  __shared__ float sW1[EDF * HH];
  __shared__ float sb1[HH];
  __shared__ unsigned short sQ[4][HH * MM];
  int tid = threadIdx.x;
  for (int i = tid; i < EDF * HH; i += 256) sW1[i] = W1[i];
  if (tid < HH) sb1[tid] = b1[tid];
  __syncthreads();

  int wid = tid >> 6, lane = tid & 63;
  int n = blockIdx.x * 4 + wid;
  int l15 = lane & 15, l4 = lane >> 4;
  int count = cnt[n];
  if (count == 0) return;

  // stage Qn[n]: LDS row r holds Qn k=qinv(r); writes linear, source permuted
  {
    const unsigned short* q = Qn + (size_t)n * (HH * MM);
#pragma unroll
    for (int i = 0; i < 4; ++i) {
      int r = i * 32 + (lane >> 1);
      int c = (lane & 1) * 8;
      uint4 v = *(const uint4*)(q + qinv(r) * 16 + c);
      *(uint4*)&sQ[wid][i * 512 + lane * 8] = v;
    }
  }
  float b2v = B2[(size_t)n * MM + l15];
  __builtin_amdgcn_s_waitcnt(0);  // wave-local LDS writes complete

  const float* eab = ea_s + (size_t)n * CAP * 4;
  const int* dsb = dst_s + (size_t)n * CAP;
  for (int t0 = 0; t0 < count; t0 += 16) {
    int rr = t0 + l15;
    bool valid = rr < count;
    float4 eav = valid ? *(const float4*)&eab[(size_t)rr * 4]
                       : make_float4(0.f, 0.f, 0.f, 0.f);
    f32x4 acc = {0.f, 0.f, 0.f, 0.f};
#pragma unroll
    for (int ks = 0; ks < 4; ++ks) {
      short8 a, b;
#pragma unroll
      for (int j = 0; j < 8; ++j) {
        int k = ks * 32 + l4 * 8 + j;
        float r = fmaf(eav.w, sW1[3 * HH + k],
                   fmaf(eav.z, sW1[2 * HH + k],
                     fmaf(eav.y, sW1[HH + k], fmaf(eav.x, sW1[k], sb1[k]))));
        a[j] = valid ? (short)f2bf(fmaxf(r, 0.f)) : (short)0;
        b[j] = (short)sQ[wid][qperm(k) * 16 + l15];
      }
      acc = __builtin_amdgcn_mfma_f32_16x16x32_bf16(a, b, acc, 0, 0, 0);
    }
#pragma unroll
    for (int j = 0; j < 4; ++j) {
      int r = t0 + l4 * 4 + j;
      if (r < count) {
        atomicAdd(&agg[(size_t)dsb[r] * MM + l15], acc[j] + b2v);
      }
    }
  }
}

// 16 nodes/block, slim: xm = agg/deg + Xroot + cbias ; hp = resid + xm@msgW + msgb
// fused BN partial sums; zeroes its agg slice for next layer.
__global__ __launch_bounds__(256) void node_update_k(
    const unsigned short* __restrict__ hb, const float* __restrict__ hsrc_pre,
    const float* __restrict__ bnsums, const float* __restrict__ gamma,
    const float* __restrict__ beta, int bn_mode,
    float* __restrict__ agg, const float* __restrict__ deg,
    const float* __restrict__ Xroot, const float* __restrict__ cbias,
    const float* __restrict__ msgW, const float* __restrict__ msgb,
    float* __restrict__ hpre, float* __restrict__ sums) {
  __shared__ float smw[MM * HH];
  __shared__ float xm[16][MM];
  __shared__ float scb[MM];
  __shared__ float smb[HH];
  __shared__ float red[256];
  __shared__ float sscl[HH], sshf[HH];
  int tid = threadIdx.x;
  int n0 = blockIdx.x * 16;
  for (int i = tid; i < MM * HH; i += 256) smw[i] = msgW[i];
  if (tid < MM) scb[tid] = cbias[tid];
  if (tid < HH) smb[tid] = msgb[tid];
  if (bn_mode && tid < HH) {
    float mu = bnsums[tid] * (1.0f / NN);
    float var = bnsums[HH + tid] * (1.0f / NN) - mu * mu;
    float sc = gamma[tid] * rsqrtf(var + BN_EPS);
    sscl[tid] = sc;
    sshf[tid] = beta[tid] - mu * sc;
  }
  __syncthreads();

  {
    int ni = tid >> 4, m = tid & 15;
    int n = n0 + ni;
    size_t idx = (size_t)n * MM + m;
    xm[ni][m] = agg[idx] / fmaxf(deg[n], 1.0f) + Xroot[idx] + scb[m];
  }
  __syncthreads();
  agg[(size_t)n0 * MM + tid] = 0.f;  // zero this block's slice for next layer

  int t = tid & 127;
  float lsum = 0.f, lss = 0.f;
#pragma unroll
  for (int pass = 0; pass < 8; ++pass) {
    int ni = pass * 2 + (tid >> 7);
    size_t idx = (size_t)(n0 + ni) * HH + t;
    float resid;
    if (bn_mode) {
      resid = fmaxf(0.f, fmaf(hsrc_pre[idx], sscl[t], sshf[t]));
    } else {
      resid = bf2f(hb[idx]);
    }
    float hp = resid + smb[t];
#pragma unroll
    for (int m = 0; m < MM; ++m) hp = fmaf(xm[ni][m], smw[m * HH + t], hp);
    hpre[idx] = hp;
    lsum += hp;
    lss = fmaf(hp, hp, lss);
  }
  red[tid] = lsum;
  __syncthreads();
  if (tid < 128) atomicAdd(&sums[t], red[tid] + red[tid + 128]);
  __syncthreads();
  red[tid] = lss;
  __syncthreads();
  if (tid < 128) atomicAdd(&sums[HH + t], red[tid] + red[tid + 128]);
}

__global__ void out_proj_k(const float* __restrict__ hpre,
                           const float* __restrict__ bnsums,
                           const float* __restrict__ gamma,
                           const float* __restrict__ beta,
                           const float* __restrict__ W, const float* __restrict__ b,
                           float* __restrict__ out) {
  __shared__ float sscl[HH], sshf[HH];
  int tid = threadIdx.x;
  if (tid < HH) {
    float mu = bnsums[tid] * (1.0f / NN);
    float var = bnsums[HH + tid] * (1.0f / NN) - mu * mu;
    float sc = gamma[tid] * rsqrtf(var + BN_EPS);
    sscl[tid] = sc;
    sshf[tid] = beta[tid] - mu * sc;
  }
  __syncthreads();
  int n = blockIdx.x * 4 + (tid >> 6);
  int lane = tid & 63;
  if (n >= NN) return;
  float acc0 = 0.f, acc1 = 0.f, acc2 = 0.f, acc3 = 0.f;
#pragma unroll
  for (int rep = 0; rep < 2; ++rep) {
    int hh = lane + rep * 64;
    float hv = fmaxf(0.f, fmaf(hpre[(size_t)n * HH + hh], sscl[hh], sshf[hh]));
    acc0 = fmaf(hv, W[hh * OUTF + 0], acc0);
    acc1 = fmaf(hv, W[hh * OUTF + 1], acc1);
    acc2 = fmaf(hv, W[hh * OUTF + 2], acc2);
    acc3 = fmaf(hv, W[hh * OUTF + 3], acc3);
  }
#pragma unroll
  for (int s = 32; s > 0; s >>= 1) {
    acc0 += __shfl_down(acc0, s);
    acc1 += __shfl_down(acc1, s);
    acc2 += __shfl_down(acc2, s);
    acc3 += __shfl_down(acc3, s);
  }
  if (lane == 0) {
    out[n * OUTF + 0] = acc0 + b[0];
    out[n * OUTF + 1] = acc1 + b[1];
    out[n * OUTF + 2] = acc2 + b[2];
    out[n * OUTF + 3] = acc3 + b[3];
  }
}

extern "C" void kernel_launch(void* const* d_in, const int* in_sizes, int n_in,
                              void* d_out, int out_size, void* d_ws, size_t ws_size,
                              hipStream_t stream) {
  (void)in_sizes; (void)n_in; (void)out_size; (void)ws_size;
  const float* x    = (const float*)d_in[0];
  const int* ei     = (const int*)d_in[1];
  const float* ea   = (const float*)d_in[2];
  const float* inW  = (const float*)d_in[3];
  const float* inb  = (const float*)d_in[4];
  const float* cW1  = (const float*)d_in[5];
  const float* cb1  = (const float*)d_in[6];
  const float* cW2  = (const float*)d_in[7];
  const float* cb2  = (const float*)d_in[8];
  const float* rW   = (const float*)d_in[9];
  const float* cbias= (const float*)d_in[10];
  const float* gam  = (const float*)d_in[11];
  const float* bet  = (const float*)d_in[12];
  const float* mW   = (const float*)d_in[13];
  const float* mb   = (const float*)d_in[14];
  const float* oW   = (const float*)d_in[15];
  const float* ob   = (const float*)d_in[16];
  float* out = (float*)d_out;

  float* ws = (float*)d_ws;
  size_t off = 0;
  // contiguous zero region: deg, cnt, sums0, sums1 (one small memset)
  float* deg   = ws + off; off += 8192;
  int* cnt     = (int*)(ws + off); off += 8192;
  float* sums0 = ws + off; off += 256;
  float* sums1 = ws + off; off += 256;
  size_t zero_floats = off;
  float* agg   = ws + off; off += (size_t)NN * MM;      // zeroed by front_k
  float* hpre0 = ws + off; off += (size_t)NN * HH;
  float* hpre1 = ws + off; off += (size_t)NN * HH;
  float* B2    = ws + off; off += (size_t)NPAD * MM;
  float* Xroot = ws + off; off += (size_t)NPAD * MM;
  unsigned short* hb = (unsigned short*)(ws + off); off += (size_t)NN * HH / 2;
  unsigned short* Bp = (unsigned short*)(ws + off); off += (size_t)NL * BPR * HH / 2;
  unsigned short* Qn = (unsigned short*)(ws + off); off += (size_t)NPAD * HH * MM / 2;
  float* ea_s  = ws + off; off += (size_t)NN * CAP * 4;
  int* dst_s   = (int*)(ws + off); off += (size_t)NN * CAP;

  hipMemsetAsync(deg, 0, zero_floats * sizeof(float), stream);
  front_k<<<NN, 128, 0, stream>>>(x, inW, inb, ei, ea, cW2, cb2, rW, hb,
                                  deg, cnt, Bp, agg, ea_s, dst_s);

  dim3 gg(17, NPAD / 128);
  // ---- layer 0 ----
  gemm_qn_k<<<gg, 256, 0, stream>>>(hb, hpre0, sums0, gam, bet, 0, Bp, Qn, B2, Xroot);
  contract_k<<<NN / 4, 256, 0, stream>>>(ea_s, dst_s, cnt, cW1, cb1, Qn, B2, agg);
  node_update_k<<<NN / 16, 256, 0, stream>>>(hb, hpre0, sums0, gam, bet, 0,
                                             agg, deg, Xroot, cbias, mW, mb,
                                             hpre0, sums0);
  // ---- layer 1 ----
  gemm_qn_k<<<gg, 256, 0, stream>>>(hb, hpre0, sums0, gam, bet, 1,
                                    Bp + (size_t)BPR * HH, Qn, B2, Xroot);
  contract_k<<<NN / 4, 256, 0, stream>>>(ea_s, dst_s, cnt, cW1 + EDF * HH,
                                         cb1 + HH, Qn, B2, agg);
  node_update_k<<<NN / 16, 256, 0, stream>>>(hb, hpre0, sums0, gam, bet, 1,
                                             agg, deg, Xroot, cbias + MM,
                                             mW + MM * HH, mb + HH,
                                             hpre1, sums1);
  out_proj_k<<<NN / 4, 256, 0, stream>>>(hpre1, sums1, gam + HH, bet + HH,
                                         oW, ob, out);
}

// Round 11
// 147.897 us; speedup vs baseline: 1.0275x; 1.0275x over previous
//
#include <hip/hip_runtime.h>

#define NN 8000
#define NPAD 8064
#define NE 64000
#define INF 16
#define HH 128
#define MM 16
#define EDF 4
#define OUTF 4
#define NL 2
#define BN_EPS 1e-5f
#define BPR 2080          // Bp rows per layer: 2048 qn-cols + 16 b2-cols + 16 rootW-cols
#define CAP 48            // per-node edge bucket capacity (Poisson(8): P(deg>=48)~1e-20)

typedef __attribute__((ext_vector_type(8))) short short8;
typedef __attribute__((ext_vector_type(4))) float f32x4;

static __device__ __forceinline__ unsigned short f2bf(float f) {
  unsigned u = __builtin_bit_cast(unsigned, f);
  u = (u + 0x7fffu + ((u >> 16) & 1u)) >> 16;
  return (unsigned short)u;
}
static __device__ __forceinline__ float bf2f(unsigned short s) {
  unsigned u = ((unsigned)s) << 16;
  return __builtin_bit_cast(float, u);
}

// bijective k-permutation for contract LDS layout, and its inverse
static __device__ __forceinline__ int qperm(int k) {
  return ((k >> 3) & 3) | ((k & 7) << 2) | (k & 0x60);
}
static __device__ __forceinline__ int qinv(int r) {
  return ((r & 3) << 3) | ((r >> 2) & 7) | (r & 0x60);
}

// in_proj (all blocks) + edge bucket-scatter (0..499) + Bp build (500..759) + agg zero (760..884)
__global__ __launch_bounds__(128) void front_k(
    const float* __restrict__ x, const float* __restrict__ inW,
    const float* __restrict__ inb, const int* __restrict__ ei,
    const float* __restrict__ ea,
    const float* __restrict__ W2, const float* __restrict__ b2,
    const float* __restrict__ rW,
    unsigned short* __restrict__ hb,
    float* __restrict__ deg, int* __restrict__ cnt,
    unsigned short* __restrict__ Bp, float* __restrict__ agg,
    float* __restrict__ ea_s, int* __restrict__ dst_s) {
  int blk = blockIdx.x;
  int t = threadIdx.x;
  __shared__ float sx[INF];
  if (t < INF) sx[t] = x[blk * INF + t];
  __syncthreads();
  float acc = inb[t];
#pragma unroll
  for (int i = 0; i < INF; ++i) acc = fmaf(sx[i], inW[i * HH + t], acc);
  hb[(size_t)blk * HH + t] = f2bf(acc);

  if (blk < 500) {
    int e = blk * 128 + t;
    int src = ei[e], dst = ei[NE + e];
    atomicAdd(&deg[dst], 1.0f);
    int slot = atomicAdd(&cnt[src], 1);
    int p = src * CAP + slot;
    *(float4*)&ea_s[(size_t)p * 4] = *(const float4*)&ea[(size_t)e * 4];
    dst_s[p] = dst;
  } else if (blk < 756) {
    // transpose one W2 row k: read 2048 f32 contiguous, write 16 Bp rows coalesced
    int r = blk - 500;            // 0..255
    int l = r >> 7, k = r & 127;
    const float* w2row = W2 + (size_t)l * (HH * HH * MM) + (size_t)k * 2048;
    float4 v0 = *(const float4*)&w2row[t * 16 + 0];
    float4 v1 = *(const float4*)&w2row[t * 16 + 4];
    float4 v2 = *(const float4*)&w2row[t * 16 + 8];
    float4 v3 = *(const float4*)&w2row[t * 16 + 12];
    unsigned short* bpr = Bp + ((size_t)l * BPR + (size_t)k * 16) * HH + t;
#pragma unroll
    for (int j = 0; j < 4; ++j) bpr[(0 + j) * HH] = f2bf((&v0.x)[j]);
#pragma unroll
    for (int j = 0; j < 4; ++j) bpr[(4 + j) * HH] = f2bf((&v1.x)[j]);
#pragma unroll
    for (int j = 0; j < 4; ++j) bpr[(8 + j) * HH] = f2bf((&v2.x)[j]);
#pragma unroll
    for (int j = 0; j < 4; ++j) bpr[(12 + j) * HH] = f2bf((&v3.x)[j]);
  } else if (blk < 760) {
    // b2 rows (756,757) at Bp row 2048; rootW rows (758,759) at Bp row 2064
    int isroot = (blk >= 758);
    int l = (blk - 756) & 1;
    const float* src = isroot ? (rW + (size_t)l * HH * MM) : (b2 + (size_t)l * 2048);
    float4 v0 = *(const float4*)&src[t * 16 + 0];
    float4 v1 = *(const float4*)&src[t * 16 + 4];
    float4 v2 = *(const float4*)&src[t * 16 + 8];
    float4 v3 = *(const float4*)&src[t * 16 + 12];
    unsigned short* bpr = Bp + ((size_t)l * BPR + 2048 + isroot * 16) * HH + t;
#pragma unroll
    for (int j = 0; j < 4; ++j) bpr[(0 + j) * HH] = f2bf((&v0.x)[j]);
#pragma unroll
    for (int j = 0; j < 4; ++j) bpr[(4 + j) * HH] = f2bf((&v1.x)[j]);
#pragma unroll
    for (int j = 0; j < 4; ++j) bpr[(8 + j) * HH] = f2bf((&v2.x)[j]);
#pragma unroll
    for (int j = 0; j < 4; ++j) bpr[(12 + j) * HH] = f2bf((&v3.x)[j]);
  } else if (blk < 885) {
    // zero agg: 125 blocks x 128 thr x 2 uint4 = 32000 uint4 = NN*MM f32
    int i = (blk - 760) * 256 + t;
    uint4 z = make_uint4(0, 0, 0, 0);
    ((uint4*)agg)[i] = z;
    ((uint4*)agg)[i + 128] = z;
  }
}

// Qn[NPAD x 2048](bf16) = A[NPAD x 128] @ Bp^T ; grid (9, 63).
// Block (bn,bm): stages A once, loops 2 B-chunks {bn*2, bn*2+1}; bn==8 -> chunk 16
// (B2[NPAD x 16] + Xroot[NPAD x 16], f32).
__global__ __launch_bounds__(256) void gemm_qn_k(
    const unsigned short* __restrict__ hb, const float* __restrict__ hpre,
    const float* __restrict__ bnsums, const float* __restrict__ gamma,
    const float* __restrict__ beta, int bn_mode,
    const unsigned short* __restrict__ Bp,
    unsigned short* __restrict__ Qn, float* __restrict__ B2,
    float* __restrict__ Xroot) {
  __shared__ unsigned short sA[16384];
  __shared__ unsigned short sB[16384];
  int tid = threadIdx.x;
  int bm = blockIdx.y, bn = blockIdx.x;
  int r0 = bm * 128;

  // ---- A staging (once per block) ----
  if (bn_mode == 0) {
#pragma unroll
    for (int rr = 0; rr < 8; ++rr) {
      int s = rr * 256 + tid;
      int row = s >> 4, k8 = s & 15;
      int n = r0 + row;
      uint4 v = make_uint4(0, 0, 0, 0);
      if (n < NN) v = *(const uint4*)&hb[(size_t)n * HH + k8 * 8];
      *(uint4*)&sA[(s ^ ((s >> 4) & 7)) * 8] = v;
    }
  } else {
    int k8 = tid & 15;
    int c0 = k8 * 8;
    float scl[8], shf[8];
#pragma unroll
    for (int j = 0; j < 8; ++j) {
      int c = c0 + j;
      float mu = bnsums[c] * (1.0f / NN);
      float var = bnsums[HH + c] * (1.0f / NN) - mu * mu;
      float sc = gamma[c] * rsqrtf(var + BN_EPS);
      scl[j] = sc;
      shf[j] = beta[c] - mu * sc;
    }
#pragma unroll
    for (int rr = 0; rr < 8; ++rr) {
      int s = rr * 256 + tid;
      int row = s >> 4;
      int n = r0 + row;
      short8 o = {0, 0, 0, 0, 0, 0, 0, 0};
      if (n < NN) {
        float4 v0 = *(const float4*)&hpre[(size_t)n * HH + c0];
        float4 v1 = *(const float4*)&hpre[(size_t)n * HH + c0 + 4];
#pragma unroll
        for (int j = 0; j < 4; ++j) {
          o[j] = (short)f2bf(fmaxf(0.f, fmaf((&v0.x)[j], scl[j], shf[j])));
          o[4 + j] = (short)f2bf(fmaxf(0.f, fmaf((&v1.x)[j], scl[4 + j], shf[4 + j])));
        }
      }
      *(short8*)&sA[(s ^ ((s >> 4) & 7)) * 8] = o;
    }
  }

  int wid = tid >> 6, lane = tid & 63;
  int wr = (wid >> 1) * 64;
  int wc = (wid & 1) * 64;
  int l15 = lane & 15, l4 = lane >> 4;

  int nchunk = (bn < 8) ? 2 : 1;
  for (int half = 0; half < nchunk; ++half) {
    int chunk = (bn < 8) ? (bn * 2 + half) : 16;

    // ---- B staging for this chunk ----
    if (chunk < 16) {
      const uint4* gB = (const uint4*)(Bp + (size_t)chunk * 128 * HH);
#pragma unroll
      for (int rr = 0; rr < 8; ++rr) {
        int s = rr * 256 + tid;
        uint4 v = gB[s];
        *(uint4*)&sB[(s ^ ((s >> 4) & 7)) * 8] = v;
      }
    } else {
      const uint4* gB = (const uint4*)(Bp + (size_t)2048 * HH);
#pragma unroll
      for (int rr = 0; rr < 8; ++rr) {
        int s = rr * 256 + tid;
        int row = s >> 4;
        uint4 v = make_uint4(0, 0, 0, 0);
        if (row < 32) v = gB[s];
        *(uint4*)&sB[(s ^ ((s >> 4) & 7)) * 8] = v;
      }
    }
    __syncthreads();

    f32x4 acc[4][4] = {};
#pragma unroll
    for (int ks = 0; ks < 4; ++ks) {
      short8 af[4], bfr[4];
      int kb = ks * 4 + l4;
#pragma unroll
      for (int mr = 0; mr < 4; ++mr) {
        int r = wr + mr * 16 + l15;
        af[mr] = *(const short8*)&sA[(r * 16 + (kb ^ (r & 7))) * 8];
      }
#pragma unroll
      for (int nc = 0; nc < 4; ++nc) {
        int r = wc + nc * 16 + l15;
        bfr[nc] = *(const short8*)&sB[(r * 16 + (kb ^ (r & 7))) * 8];
      }
#pragma unroll
      for (int mr = 0; mr < 4; ++mr)
#pragma unroll
        for (int nc = 0; nc < 4; ++nc)
          acc[mr][nc] = __builtin_amdgcn_mfma_f32_16x16x32_bf16(af[mr], bfr[nc], acc[mr][nc], 0, 0, 0);
    }

    if (chunk < 16) {
#pragma unroll
      for (int mr = 0; mr < 4; ++mr) {
        int rr0 = r0 + wr + mr * 16 + l4 * 4;
#pragma unroll
        for (int nc = 0; nc < 4; ++nc) {
          int c0 = chunk * 128 + wc + nc * 16 + l15;
#pragma unroll
          for (int j = 0; j < 4; ++j)
            Qn[(size_t)(rr0 + j) * (HH * MM) + c0] = f2bf(acc[mr][nc][j]);
        }
      }
    } else if (wc == 0) {
#pragma unroll
      for (int mr = 0; mr < 4; ++mr) {
        int rr0 = r0 + wr + mr * 16 + l4 * 4;
#pragma unroll
        for (int j = 0; j < 4; ++j) {
          B2[(size_t)(rr0 + j) * MM + l15] = acc[mr][0][j];
          Xroot[(size_t)(rr0 + j) * MM + l15] = acc[mr][1][j];
        }
      }
    }
    __syncthreads();  // guard sB overwrite on next chunk
  }
}

// One wave per src node: P[d x 16] = relu1[d x 128] @ Qn[n][128 x 16] via MFMA.
// Bucketed edges; LDS staging linear ds_write + pre-permuted global source.
__global__ __launch_bounds__(256) void contract_k(const float* __restrict__ ea_s,
                                                  const int* __restrict__ dst_s,
                                                  const int* __restrict__ cnt,
                                                  const float* __restrict__ W1,
                                                  const float* __restrict__ b1,
                                                  const unsigned short* __restrict__ Qn,
                                                  const float* __restrict__ B2,
                                                  float* __restrict__ agg) {
  __shared__ float sW1[EDF * HH];
  __shared__ float sb1[HH];
  __shared__ unsigned short sQ[4][HH * MM];
  int tid = threadIdx.x;
  for (int i = tid; i < EDF * HH; i += 256) sW1[i] = W1[i];
  if (tid < HH) sb1[tid] = b1[tid];
  __syncthreads();

  int wid = tid >> 6, lane = tid & 63;
  int n = blockIdx.x * 4 + wid;
  int l15 = lane & 15, l4 = lane >> 4;
  int count = cnt[n];
  if (count == 0) return;

  // stage Qn[n]: LDS row r holds Qn k=qinv(r); writes linear, source permuted
  {
    const unsigned short* q = Qn + (size_t)n * (HH * MM);
#pragma unroll
    for (int i = 0; i < 4; ++i) {
      int r = i * 32 + (lane >> 1);
      int c = (lane & 1) * 8;
      uint4 v = *(const uint4*)(q + qinv(r) * 16 + c);
      *(uint4*)&sQ[wid][i * 512 + lane * 8] = v;
    }
  }
  float b2v = B2[(size_t)n * MM + l15];
  __builtin_amdgcn_s_waitcnt(0);  // wave-local LDS writes complete

  const float* eab = ea_s + (size_t)n * CAP * 4;
  const int* dsb = dst_s + (size_t)n * CAP;
  for (int t0 = 0; t0 < count; t0 += 16) {
    int rr = t0 + l15;
    bool valid = rr < count;
    float4 eav = valid ? *(const float4*)&eab[(size_t)rr * 4]
                       : make_float4(0.f, 0.f, 0.f, 0.f);
    f32x4 acc = {0.f, 0.f, 0.f, 0.f};
#pragma unroll
    for (int ks = 0; ks < 4; ++ks) {
      short8 a, b;
#pragma unroll
      for (int j = 0; j < 8; ++j) {
        int k = ks * 32 + l4 * 8 + j;
        float r = fmaf(eav.w, sW1[3 * HH + k],
                   fmaf(eav.z, sW1[2 * HH + k],
                     fmaf(eav.y, sW1[HH + k], fmaf(eav.x, sW1[k], sb1[k]))));
        a[j] = valid ? (short)f2bf(fmaxf(r, 0.f)) : (short)0;
        b[j] = (short)sQ[wid][qperm(k) * 16 + l15];
      }
      acc = __builtin_amdgcn_mfma_f32_16x16x32_bf16(a, b, acc, 0, 0, 0);
    }
#pragma unroll
    for (int j = 0; j < 4; ++j) {
      int r = t0 + l4 * 4 + j;
      if (r < count) {
        atomicAdd(&agg[(size_t)dsb[r] * MM + l15], acc[j] + b2v);
      }
    }
  }
}

// 16 nodes/block, slim: xm = agg/deg + Xroot + cbias ; hp = resid + xm@msgW + msgb
// fused BN partial sums; zeroes its agg slice for next layer.
__global__ __launch_bounds__(256) void node_update_k(
    const unsigned short* __restrict__ hb, const float* __restrict__ hsrc_pre,
    const float* __restrict__ bnsums, const float* __restrict__ gamma,
    const float* __restrict__ beta, int bn_mode,
    float* __restrict__ agg, const float* __restrict__ deg,
    const float* __restrict__ Xroot, const float* __restrict__ cbias,
    const float* __restrict__ msgW, const float* __restrict__ msgb,
    float* __restrict__ hpre, float* __restrict__ sums) {
  __shared__ float smw[MM * HH];
  __shared__ float xm[16][MM];
  __shared__ float scb[MM];
  __shared__ float smb[HH];
  __shared__ float red[256];
  __shared__ float sscl[HH], sshf[HH];
  int tid = threadIdx.x;
  int n0 = blockIdx.x * 16;
  for (int i = tid; i < MM * HH; i += 256) smw[i] = msgW[i];
  if (tid < MM) scb[tid] = cbias[tid];
  if (tid < HH) smb[tid] = msgb[tid];
  if (bn_mode && tid < HH) {
    float mu = bnsums[tid] * (1.0f / NN);
    float var = bnsums[HH + tid] * (1.0f / NN) - mu * mu;
    float sc = gamma[tid] * rsqrtf(var + BN_EPS);
    sscl[tid] = sc;
    sshf[tid] = beta[tid] - mu * sc;
  }
  __syncthreads();

  {
    int ni = tid >> 4, m = tid & 15;
    int n = n0 + ni;
    size_t idx = (size_t)n * MM + m;
    xm[ni][m] = agg[idx] / fmaxf(deg[n], 1.0f) + Xroot[idx] + scb[m];
  }
  __syncthreads();
  agg[(size_t)n0 * MM + tid] = 0.f;  // zero this block's slice for next layer

  int t = tid & 127;
  float lsum = 0.f, lss = 0.f;
#pragma unroll
  for (int pass = 0; pass < 8; ++pass) {
    int ni = pass * 2 + (tid >> 7);
    size_t idx = (size_t)(n0 + ni) * HH + t;
    float resid;
    if (bn_mode) {
      resid = fmaxf(0.f, fmaf(hsrc_pre[idx], sscl[t], sshf[t]));
    } else {
      resid = bf2f(hb[idx]);
    }
    float hp = resid + smb[t];
#pragma unroll
    for (int m = 0; m < MM; ++m) hp = fmaf(xm[ni][m], smw[m * HH + t], hp);
    hpre[idx] = hp;
    lsum += hp;
    lss = fmaf(hp, hp, lss);
  }
  red[tid] = lsum;
  __syncthreads();
  if (tid < 128) atomicAdd(&sums[t], red[tid] + red[tid + 128]);
  __syncthreads();
  red[tid] = lss;
  __syncthreads();
  if (tid < 128) atomicAdd(&sums[HH + t], red[tid] + red[tid + 128]);
}

__global__ void out_proj_k(const float* __restrict__ hpre,
                           const float* __restrict__ bnsums,
                           const float* __restrict__ gamma,
                           const float* __restrict__ beta,
                           const float* __restrict__ W, const float* __restrict__ b,
                           float* __restrict__ out) {
  __shared__ float sscl[HH], sshf[HH];
  int tid = threadIdx.x;
  if (tid < HH) {
    float mu = bnsums[tid] * (1.0f / NN);
    float var = bnsums[HH + tid] * (1.0f / NN) - mu * mu;
    float sc = gamma[tid] * rsqrtf(var + BN_EPS);
    sscl[tid] = sc;
    sshf[tid] = beta[tid] - mu * sc;
  }
  __syncthreads();
  int n = blockIdx.x * 4 + (tid >> 6);
  int lane = tid & 63;
  if (n >= NN) return;
  float acc0 = 0.f, acc1 = 0.f, acc2 = 0.f, acc3 = 0.f;
#pragma unroll
  for (int rep = 0; rep < 2; ++rep) {
    int hh = lane + rep * 64;
    float hv = fmaxf(0.f, fmaf(hpre[(size_t)n * HH + hh], sscl[hh], sshf[hh]));
    acc0 = fmaf(hv, W[hh * OUTF + 0], acc0);
    acc1 = fmaf(hv, W[hh * OUTF + 1], acc1);
    acc2 = fmaf(hv, W[hh * OUTF + 2], acc2);
    acc3 = fmaf(hv, W[hh * OUTF + 3], acc3);
  }
#pragma unroll
  for (int s = 32; s > 0; s >>= 1) {
    acc0 += __shfl_down(acc0, s);
    acc1 += __shfl_down(acc1, s);
    acc2 += __shfl_down(acc2, s);
    acc3 += __shfl_down(acc3, s);
  }
  if (lane == 0) {
    out[n * OUTF + 0] = acc0 + b[0];
    out[n * OUTF + 1] = acc1 + b[1];
    out[n * OUTF + 2] = acc2 + b[2];
    out[n * OUTF + 3] = acc3 + b[3];
  }
}

extern "C" void kernel_launch(void* const* d_in, const int* in_sizes, int n_in,
                              void* d_out, int out_size, void* d_ws, size_t ws_size,
                              hipStream_t stream) {
  (void)in_sizes; (void)n_in; (void)out_size; (void)ws_size;
  const float* x    = (const float*)d_in[0];
  const int* ei     = (const int*)d_in[1];
  const float* ea   = (const float*)d_in[2];
  const float* inW  = (const float*)d_in[3];
  const float* inb  = (const float*)d_in[4];
  const float* cW1  = (const float*)d_in[5];
  const float* cb1  = (const float*)d_in[6];
  const float* cW2  = (const float*)d_in[7];
  const float* cb2  = (const float*)d_in[8];
  const float* rW   = (const float*)d_in[9];
  const float* cbias= (const float*)d_in[10];
  const float* gam  = (const float*)d_in[11];
  const float* bet  = (const float*)d_in[12];
  const float* mW   = (const float*)d_in[13];
  const float* mb   = (const float*)d_in[14];
  const float* oW   = (const float*)d_in[15];
  const float* ob   = (const float*)d_in[16];
  float* out = (float*)d_out;

  float* ws = (float*)d_ws;
  size_t off = 0;
  // contiguous zero region: deg, cnt, sums0, sums1 (one small memset)
  float* deg   = ws + off; off += 8192;
  int* cnt     = (int*)(ws + off); off += 8192;
  float* sums0 = ws + off; off += 256;
  float* sums1 = ws + off; off += 256;
  size_t zero_floats = off;
  float* agg   = ws + off; off += (size_t)NN * MM;      // zeroed by front_k
  float* hpre0 = ws + off; off += (size_t)NN * HH;
  float* hpre1 = ws + off; off += (size_t)NN * HH;
  float* B2    = ws + off; off += (size_t)NPAD * MM;
  float* Xroot = ws + off; off += (size_t)NPAD * MM;
  unsigned short* hb = (unsigned short*)(ws + off); off += (size_t)NN * HH / 2;
  unsigned short* Bp = (unsigned short*)(ws + off); off += (size_t)NL * BPR * HH / 2;
  unsigned short* Qn = (unsigned short*)(ws + off); off += (size_t)NPAD * HH * MM / 2;
  float* ea_s  = ws + off; off += (size_t)NN * CAP * 4;
  int* dst_s   = (int*)(ws + off); off += (size_t)NN * CAP;

  hipMemsetAsync(deg, 0, zero_floats * sizeof(float), stream);
  front_k<<<NN, 128, 0, stream>>>(x, inW, inb, ei, ea, cW2, cb2, rW, hb,
                                  deg, cnt, Bp, agg, ea_s, dst_s);

  dim3 gg(9, NPAD / 128);
  // ---- layer 0 ----
  gemm_qn_k<<<gg, 256, 0, stream>>>(hb, hpre0, sums0, gam, bet, 0, Bp, Qn, B2, Xroot);
  contract_k<<<NN / 4, 256, 0, stream>>>(ea_s, dst_s, cnt, cW1, cb1, Qn, B2, agg);
  node_update_k<<<NN / 16, 256, 0, stream>>>(hb, hpre0, sums0, gam, bet, 0,
                                             agg, deg, Xroot, cbias, mW, mb,
                                             hpre0, sums0);
  // ---- layer 1 ----
  gemm_qn_k<<<gg, 256, 0, stream>>>(hb, hpre0, sums0, gam, bet, 1,
                                    Bp + (size_t)BPR * HH, Qn, B2, Xroot);
  contract_k<<<NN / 4, 256, 0, stream>>>(ea_s, dst_s, cnt, cW1 + EDF * HH,
                                         cb1 + HH, Qn, B2, agg);
  node_update_k<<<NN / 16, 256, 0, stream>>>(hb, hpre0, sums0, gam, bet, 1,
                                             agg, deg, Xroot, cbias + MM,
                                             mW + MM * HH, mb + HH,
                                             hpre1, sums1);
  out_proj_k<<<NN / 4, 256, 0, stream>>>(hpre1, sums1, gam + HH, bet + HH,
                                         oW, ob, out);
}